// Round 6
// baseline (75.254 us; speedup 1.0000x reference)
//
#include <hip/hip_runtime.h>

#define HOG_PI  3.14159265358979323846f
#define HOG_PI2 1.57079632679489661923f

// Accumulate 4 pixels (one float4 column) into 9-bin register histogram.
__device__ __forceinline__ void accum_quad(
    const float4 c0, const float4 c1, const float4 c2,
    const float4 p0, const float4 p1, const float4 p2,
    const float4 n0, const float4 n1, const float4 n2,
    int lm, int lp, int xq, float h[9]) {
  float dxv[3][4], dyv[3][4];
#pragma unroll
  for (int c = 0; c < 3; ++c) {
    const float4 cc = (c == 0) ? c0 : (c == 1) ? c1 : c2;
    const float4 pp = (c == 0) ? p0 : (c == 1) ? p1 : p2;
    const float4 nn = (c == 0) ? n0 : (c == 1) ? n1 : n2;
    float lf = __shfl(cc.w, lm, 64);
    float rf = __shfl(cc.x, lp, 64);
    if (xq == 0) lf = cc.x;
    if (xq == 31) rf = cc.w;
    dxv[c][0] = cc.y - lf;
    dxv[c][1] = cc.z - cc.x;
    dxv[c][2] = cc.w - cc.y;
    dxv[c][3] = rf - cc.z;
    dyv[c][0] = nn.x - pp.x;
    dyv[c][1] = nn.y - pp.y;
    dyv[c][2] = nn.z - pp.z;
    dyv[c][3] = nn.w - pp.w;
  }
#pragma unroll
  for (int i = 0; i < 4; ++i) {
    // channel argmax, first-max wins on ties (strict >)
    float dxs = dxv[0][i], dys = dyv[0][i];
    float g = dxs * dxs + dys * dys;
    const float g1 = dxv[1][i] * dxv[1][i] + dyv[1][i] * dyv[1][i];
    if (g1 > g) { dxs = dxv[1][i]; dys = dyv[1][i]; g = g1; }
    const float g2 = dxv[2][i] * dxv[2][i] + dyv[2][i] * dyv[2][i];
    if (g2 > g) { dxs = dxv[2][i]; dys = dyv[2][i]; g = g2; }
    const float mag = sqrtf(g);
    // unsigned angle mod pi: flip so dy >= 0
    if (dys < 0.0f) { dys = -dys; dxs = -dxs; }
    const float ax = fabsf(dxs);
    const float mn = fminf(ax, dys), mx = fmaxf(ax, dys);
    const float a = mn * __builtin_amdgcn_rcpf(fmaxf(mx, 1e-30f));
    const float sq = a * a;
    float th = ((((0.0208351f * sq - 0.0851330f) * sq + 0.1801410f) * sq
                 - 0.3302995f) * sq + 0.9998660f) * a;
    if (dys > ax) th = HOG_PI2 - th;
    if (dxs < 0.0f) th = HOG_PI - th;
    const float pos = th * (9.0f / HOG_PI) - 0.5f;  // [-0.5, 8.5]
    const float bf = floorf(pos);
    const float frac = pos - bf;
    const int b0 = (int)bf;  // [-1, 8]
    const int b0i = (b0 < 0) ? 8 : b0;
    const int b1i = (b0i == 8) ? 0 : b0i + 1;
    const float w0 = mag * (1.0f - frac);
    const float w1 = mag * frac;
    // register histogram: static indices; b0i != b1i -> single chained select
#pragma unroll
    for (int k = 0; k < 9; ++k)
      h[k] += (b0i == k) ? w0 : ((b1i == k) ? w1 : 0.0f);
  }
}

// Two blocks per image. Half 0: cell bands 0..7, block rows 0..6.
// Half 1: cell bands 8..15 + redundant band 7, block rows 7..14.
// 256 threads = 32 float4-cols (xq) x 8 slots (s); slot s owns one band.
// Register histograms + shfl reduction; zero LDS atomics (R5's proven win).
__global__ void hog_kernel(const float* __restrict__ img,
                           const int* __restrict__ targets,
                           const int* __restrict__ camid,
                           float* __restrict__ out, int B) {
  const int bb = blockIdx.x;
  const int b = bb >> 1;
  const int half = bb & 1;
  const int t = threadIdx.x;
  const float* im = img + (size_t)b * (3 * 256 * 128);

  __shared__ float cellh[16][8][9];  // written once per entry, no atomics
  __shared__ float part[8][8][9];    // band-7 partials (half 1 only)

  const int xq = t & 31;   // float4 column 0..31
  const int s = t >> 5;    // slot 0..7
  const int x0 = xq * 4;
  const int cx = xq >> 2;  // cell column 0..7
  const int lane = t & 63;
  const int lm = (xq == 0) ? lane : lane - 1;
  const int lp = (xq == 31) ? lane : lane + 1;

  const float* ch0 = im;
  const float* ch1 = im + 32768;
  const float* ch2 = im + 65536;

  {  // main band: m = s + half*8, rows m*16 .. m*16+15, rolling 3-row window
    const int m = s + half * 8;
    const int r0 = m * 16;
    float h[9];
#pragma unroll
    for (int k = 0; k < 9; ++k) h[k] = 0.0f;

    const int rp = (r0 == 0) ? 0 : r0 - 1;
    float4 p0 = *(const float4*)(ch0 + rp * 128 + x0);
    float4 p1 = *(const float4*)(ch1 + rp * 128 + x0);
    float4 p2 = *(const float4*)(ch2 + rp * 128 + x0);
    float4 c0 = *(const float4*)(ch0 + r0 * 128 + x0);
    float4 c1 = *(const float4*)(ch1 + r0 * 128 + x0);
    float4 c2 = *(const float4*)(ch2 + r0 * 128 + x0);

    for (int r = 0; r < 16; ++r) {
      const int y = r0 + r;
      const int yn = (y == 255) ? 255 : y + 1;
      const float4 n0 = *(const float4*)(ch0 + yn * 128 + x0);
      const float4 n1 = *(const float4*)(ch1 + yn * 128 + x0);
      const float4 n2 = *(const float4*)(ch2 + yn * 128 + x0);
      accum_quad(c0, c1, c2, p0, p1, p2, n0, n1, n2, lm, lp, xq, h);
      p0 = c0; p1 = c1; p2 = c2;
      c0 = n0; c1 = n1; c2 = n2;
    }
    // reduce across the 4 lanes sharing this cell column, write once
#pragma unroll
    for (int k = 0; k < 9; ++k) {
      float v = h[k];
      v += __shfl_xor(v, 1, 64);
      v += __shfl_xor(v, 2, 64);
      if ((xq & 3) == 0) cellh[m][cx][k] = v;
    }
  }

  if (half) {  // redundant band 7 (rows 112..127): thread covers 2 rows
    float h2[9];
#pragma unroll
    for (int k = 0; k < 9; ++k) h2[k] = 0.0f;
#pragma unroll
    for (int rr = 0; rr < 2; ++rr) {
      const int y = 112 + s + rr * 8;  // 112..127, no edge clamps needed
      const float4 pp0 = *(const float4*)(ch0 + (y - 1) * 128 + x0);
      const float4 pp1 = *(const float4*)(ch1 + (y - 1) * 128 + x0);
      const float4 pp2 = *(const float4*)(ch2 + (y - 1) * 128 + x0);
      const float4 cc0 = *(const float4*)(ch0 + y * 128 + x0);
      const float4 cc1 = *(const float4*)(ch1 + y * 128 + x0);
      const float4 cc2 = *(const float4*)(ch2 + y * 128 + x0);
      const float4 nn0 = *(const float4*)(ch0 + (y + 1) * 128 + x0);
      const float4 nn1 = *(const float4*)(ch1 + (y + 1) * 128 + x0);
      const float4 nn2 = *(const float4*)(ch2 + (y + 1) * 128 + x0);
      accum_quad(cc0, cc1, cc2, pp0, pp1, pp2, nn0, nn1, nn2, lm, lp, xq, h2);
    }
#pragma unroll
    for (int k = 0; k < 9; ++k) {
      float v = h2[k];
      v += __shfl_xor(v, 1, 64);
      v += __shfl_xor(v, 2, 64);
      if ((xq & 3) == 0) part[s][cx][k] = v;
    }
  }
  __syncthreads();
  if (half && t < 72) {
    const int cxx = t / 9;
    const int k = t - cxx * 9;
    float v = 0.0f;
#pragma unroll
    for (int g = 0; g < 8; ++g) v += part[g][cxx][k];
    cellh[7][cxx][k] = v;
  }
  __syncthreads();

  float* outF = out + (size_t)b * 4096;
  const int nby = half ? 8 : 7;
  if (t < nby * 7) {
    const int byl = t / 7;
    const int bx = t - byl * 7;
    const int by = half ? 7 + byl : byl;
    float v[36];
#pragma unroll
    for (int q = 0; q < 4; ++q) {
      const int cy = by + (q >> 1);
      const int ccx = bx + (q & 1);
#pragma unroll
      for (int k = 0; k < 9; ++k) v[q * 9 + k] = cellh[cy][ccx][k];
    }
    float ss = 0.0f;
#pragma unroll
    for (int jj = 0; jj < 36; ++jj) ss += v[jj] * v[jj];
    const float s1 = 1.0f / (sqrtf(ss) + 3.6f);  // sz*0.1 = 36*0.1
    float ss2 = 0.0f;
#pragma unroll
    for (int jj = 0; jj < 36; ++jj) {
      v[jj] = fminf(v[jj] * s1, 0.2f);
      ss2 += v[jj] * v[jj];
    }
    const float s2 = 1.0f / (sqrtf(ss2) + 1e-3f);
    float4* dst = (float4*)(outF + (by * 7 + bx) * 36);
#pragma unroll
    for (int q = 0; q < 9; ++q)
      dst[q] = make_float4(v[4 * q] * s2, v[4 * q + 1] * s2,
                           v[4 * q + 2] * s2, v[4 * q + 3] * s2);
  }
  if (half) {
    // zero the pad region [3780, 4096) + passthrough outputs
    for (int i = 3780 + t; i < 4096; i += 256) outF[i] = 0.0f;
    if (t == 64) out[(size_t)B * 4096 + b] = (float)targets[b];
    if (t == 65) out[(size_t)B * 4096 + B + b] = (float)camid[b];
  }
}

extern "C" void kernel_launch(void* const* d_in, const int* in_sizes, int n_in,
                              void* d_out, int out_size, void* d_ws, size_t ws_size,
                              hipStream_t stream) {
  const float* images = (const float*)d_in[0];
  const int* targets = (const int*)d_in[1];
  const int* camid = (const int*)d_in[2];
  float* out = (float*)d_out;
  const int B = in_sizes[1];  // 512
  hipLaunchKernelGGL(hog_kernel, dim3(B * 2), dim3(256), 0, stream,
                     images, targets, camid, out, B);
}

// Round 7
// 61.403 us; speedup vs baseline: 1.2256x; 1.2256x over previous
//
#include <hip/hip_runtime.h>

#define HOG_PI  3.14159265358979323846f
#define HOG_PI2 1.57079632679489661923f

typedef float f2 __attribute__((ext_vector_type(2)));

__device__ __forceinline__ float dpp_from_left(float x) {  // lane i <- lane i-1
  return __int_as_float(__builtin_amdgcn_mov_dpp(__float_as_int(x), 0x130, 0xF, 0xF, true));
}
__device__ __forceinline__ float dpp_from_right(float x) {  // lane i <- lane i+1
  return __int_as_float(__builtin_amdgcn_mov_dpp(__float_as_int(x), 0x138, 0xF, 0xF, true));
}

// Accumulate 4 pixels (one float4 column) into tent-binned histogram
// h2[0..4] = bins {0,1},{2,3},{4,5},{6,7},{8,scratch9}.
__device__ __forceinline__ void accum_quad(
    const float4 c0, const float4 c1, const float4 c2,
    const float4 p0, const float4 p1, const float4 p2,
    const float4 n0, const float4 n1, const float4 n2,
    int xq, f2 h2[5]) {
  float dxv[3][4], dyv[3][4];
#pragma unroll
  for (int c = 0; c < 3; ++c) {
    const float4 cc = (c == 0) ? c0 : (c == 1) ? c1 : c2;
    const float4 pp = (c == 0) ? p0 : (c == 1) ? p1 : p2;
    const float4 nn = (c == 0) ? n0 : (c == 1) ? n1 : n2;
    float lf = dpp_from_left(cc.w);   // prev lane's cc.w (VALU, no DS pipe)
    float rf = dpp_from_right(cc.x);  // next lane's cc.x
    if (xq == 0) lf = cc.x;           // edge clamp overrides boundary lanes
    if (xq == 31) rf = cc.w;
    dxv[c][0] = cc.y - lf;
    dxv[c][1] = cc.z - cc.x;
    dxv[c][2] = cc.w - cc.y;
    dxv[c][3] = rf - cc.z;
    dyv[c][0] = nn.x - pp.x;
    dyv[c][1] = nn.y - pp.y;
    dyv[c][2] = nn.z - pp.z;
    dyv[c][3] = nn.w - pp.w;
  }
#pragma unroll
  for (int i = 0; i < 4; ++i) {
    // channel argmax, first-max wins on ties (strict >)
    float dxs = dxv[0][i], dys = dyv[0][i];
    float g = dxs * dxs + dys * dys;
    const float g1 = dxv[1][i] * dxv[1][i] + dyv[1][i] * dyv[1][i];
    if (g1 > g) { dxs = dxv[1][i]; dys = dyv[1][i]; g = g1; }
    const float g2 = dxv[2][i] * dxv[2][i] + dyv[2][i] * dyv[2][i];
    if (g2 > g) { dxs = dxv[2][i]; dys = dyv[2][i]; g = g2; }
    const float mag = sqrtf(g);
    // unsigned angle mod pi: flip so dy >= 0
    if (dys < 0.0f) { dys = -dys; dxs = -dxs; }
    const float ax = fabsf(dxs);
    const float mn = fminf(ax, dys), mx = fmaxf(ax, dys);
    const float a = mn * __builtin_amdgcn_rcpf(fmaxf(mx, 1e-30f));
    const float sq = a * a;
    float th = ((((0.0208351f * sq - 0.0851330f) * sq + 0.1801410f) * sq
                 - 0.3302995f) * sq + 0.9998660f) * a;
    if (dys > ax) th = HOG_PI2 - th;
    if (dxs < 0.0f) th = HOG_PI - th;
    const float pos = th * (9.0f / HOG_PI) - 0.5f;  // [-0.5, 8.5]
    // tent binning: bin k += mag*max(0, 1-|pos-k|); packed f32 pairs
    const f2 pos2 = {pos, pos};
    const f2 zero2 = {0.0f, 0.0f};
#pragma unroll
    for (int p = 0; p < 5; ++p) {
      const f2 kk = {(float)(2 * p), (float)(2 * p + 1)};
      f2 e = 1.0f - __builtin_elementwise_abs(pos2 - kk);
      e = __builtin_elementwise_max(e, zero2);
      h2[p] += mag * e;
    }
    // wrap terms: pos<0 -> bin8 gets -pos; pos>8 -> bin0 gets pos-8
    h2[4].x += mag * fmaxf(-pos, 0.0f);
    h2[0].x += mag * fmaxf(pos - 8.0f, 0.0f);
  }
}

// One block per image, 512 threads = 16 bands (m=t>>5) x 32 float4-cols (xq).
// Each thread: 16 rows of its band, rolling 3-row window, register tent
// histogram; flush via 4-lane shfl reduce + single non-atomic ds_write.
__global__ __launch_bounds__(512, 4) void hog_kernel(
    const float* __restrict__ img, const int* __restrict__ targets,
    const int* __restrict__ camid, float* __restrict__ out, int B) {
  const int b = blockIdx.x;
  const int t = threadIdx.x;
  const float* im = img + (size_t)b * (3 * 256 * 128);

  __shared__ float cellh[16][8][9];  // each entry written exactly once

  const int xq = t & 31;   // float4 column 0..31
  const int m = t >> 5;    // cell band 0..15
  const int x0 = xq * 4;
  const int cx = xq >> 2;  // cell column 0..7
  const int r0 = m * 16;

  const float* ch0 = im;
  const float* ch1 = im + 32768;
  const float* ch2 = im + 65536;

  f2 h2[5];
#pragma unroll
  for (int p = 0; p < 5; ++p) h2[p] = (f2){0.0f, 0.0f};

  const int rp = (r0 == 0) ? 0 : r0 - 1;
  float4 p0 = *(const float4*)(ch0 + rp * 128 + x0);
  float4 p1 = *(const float4*)(ch1 + rp * 128 + x0);
  float4 p2 = *(const float4*)(ch2 + rp * 128 + x0);
  float4 c0 = *(const float4*)(ch0 + r0 * 128 + x0);
  float4 c1 = *(const float4*)(ch1 + r0 * 128 + x0);
  float4 c2 = *(const float4*)(ch2 + r0 * 128 + x0);

  for (int r = 0; r < 16; ++r) {
    const int y = r0 + r;
    const int yn = (y == 255) ? 255 : y + 1;
    const float4 n0 = *(const float4*)(ch0 + yn * 128 + x0);
    const float4 n1 = *(const float4*)(ch1 + yn * 128 + x0);
    const float4 n2 = *(const float4*)(ch2 + yn * 128 + x0);
    accum_quad(c0, c1, c2, p0, p1, p2, n0, n1, n2, xq, h2);
    p0 = c0; p1 = c1; p2 = c2;
    c0 = n0; c1 = n1; c2 = n2;
  }

  // flush: reduce across the 4 lanes sharing this cell column, write once
  float hv[9] = {h2[0].x, h2[0].y, h2[1].x, h2[1].y, h2[2].x,
                 h2[2].y, h2[3].x, h2[3].y, h2[4].x};
#pragma unroll
  for (int k = 0; k < 9; ++k) {
    float v = hv[k];
    v += __shfl_xor(v, 1, 64);
    v += __shfl_xor(v, 2, 64);
    if ((xq & 3) == 0) cellh[m][cx][k] = v;
  }
  __syncthreads();

  float* outF = out + (size_t)b * 4096;
  if (t < 105) {
    const int by = t / 7;
    const int bx = t - by * 7;
    float v[36];
#pragma unroll
    for (int q = 0; q < 4; ++q) {
      const int cy = by + (q >> 1);
      const int ccx = bx + (q & 1);
#pragma unroll
      for (int k = 0; k < 9; ++k) v[q * 9 + k] = cellh[cy][ccx][k];
    }
    float ss = 0.0f;
#pragma unroll
    for (int jj = 0; jj < 36; ++jj) ss += v[jj] * v[jj];
    const float s1 = 1.0f / (sqrtf(ss) + 3.6f);  // sz*0.1 = 36*0.1
    float ss2 = 0.0f;
#pragma unroll
    for (int jj = 0; jj < 36; ++jj) {
      v[jj] = fminf(v[jj] * s1, 0.2f);
      ss2 += v[jj] * v[jj];
    }
    const float s2 = 1.0f / (sqrtf(ss2) + 1e-3f);
    float4* dst = (float4*)(outF + (by * 7 + bx) * 36);
#pragma unroll
    for (int q = 0; q < 9; ++q)
      dst[q] = make_float4(v[4 * q] * s2, v[4 * q + 1] * s2,
                           v[4 * q + 2] * s2, v[4 * q + 3] * s2);
  }
  // zero the pad region [3780, 4096)
  for (int i = 3780 + t; i < 4096; i += 512) outF[i] = 0.0f;
  // passthrough outputs
  if (t == 400) out[(size_t)B * 4096 + b] = (float)targets[b];
  if (t == 401) out[(size_t)B * 4096 + B + b] = (float)camid[b];
}

extern "C" void kernel_launch(void* const* d_in, const int* in_sizes, int n_in,
                              void* d_out, int out_size, void* d_ws, size_t ws_size,
                              hipStream_t stream) {
  const float* images = (const float*)d_in[0];
  const int* targets = (const int*)d_in[1];
  const int* camid = (const int*)d_in[2];
  float* out = (float*)d_out;
  const int B = in_sizes[1];  // 512
  hipLaunchKernelGGL(hog_kernel, dim3(B), dim3(512), 0, stream,
                     images, targets, camid, out, B);
}